// Round 2
// baseline (579.052 us; speedup 1.0000x reference)
//
#include <hip/hip_runtime.h>
#include <stdint.h>

#define BB 16
#define NN 102000
#define NCLS 35
#define RSTRIDE 40
#define PRE 1024
#define CAP 2048
#define MAXDET 300
#define NBUCK 4096
#define CONF_T 0.25f
#define IOU_T 0.45f
#define BUCK_BASE 0x3E800000u
#define SROWS 256
#define LPAD 41

// ---- workspace layout (bytes) ----
#define SCORES_OFF ((size_t)0)
#define SCORES_BYTES ((size_t)BB * NN * 4)                 // 6,528,000
#define GHIST_OFF (SCORES_OFF + SCORES_BYTES)
#define GHIST_BYTES ((size_t)BB * NBUCK * 4)               // 262,144
#define CNT_OFF (GHIST_OFF + GHIST_BYTES)                  // 64 B (16 u32 + pad)
#define CUT_OFF (CNT_OFF + 64)                             // 64 B
#define CANDS_OFF (CUT_OFF + 64)
#define CANDS_BYTES ((size_t)BB * CAP * 8)
#define BOXES_OFF (CANDS_OFF + CANDS_BYTES)
#define BOXES_BYTES ((size_t)BB * PRE * 16)
#define SVAL_OFF (BOXES_OFF + BOXES_BYTES)
#define SVAL_BYTES ((size_t)BB * PRE * 4)
#define CLS_OFF (SVAL_OFF + SVAL_BYTES)
#define CLS_BYTES ((size_t)BB * PRE * 4)
#define MASK_OFF (CLS_OFF + CLS_BYTES)
#define MASK_BYTES ((size_t)BB * PRE * 16 * 8)             // 2 MB

// ============================================================
// Kernel 1: score every box + per-batch global histogram of score bits.
// score = (obj>0.25 && conf>0.25) ? conf : 0, conf = max_j(cls_j*obj)
// Rows staged through LDS (41-pad) so global loads are fully coalesced.
// ============================================================
__global__ __launch_bounds__(256) void k_score(const float* __restrict__ pred,
                                               float* __restrict__ scores,
                                               unsigned int* __restrict__ ghist) {
    __shared__ float lds[SROWS * LPAD];        // 41,984 B
    __shared__ unsigned int hist[NBUCK];       // 16,384 B
    int b = blockIdx.y, tid = threadIdx.x;
    int rowBase = blockIdx.x * SROWS;
    int nrows = NN - rowBase; if (nrows > SROWS) nrows = SROWS;
    for (int k = tid; k < NBUCK; k += 256) hist[k] = 0u;
    const float4* gp = (const float4*)(pred + ((size_t)b * NN + rowBase) * RSTRIDE);
    int nf4 = nrows * 10;                      // 10 float4 per 40-float row
    for (int it = tid; it < nf4; it += 256) {
        float4 v = gp[it];
        int r = it / 10;
        int c = (it - r * 10) * 4;
        float* d = &lds[r * LPAD + c];
        d[0] = v.x; d[1] = v.y; d[2] = v.z; d[3] = v.w;
    }
    __syncthreads();
    if (tid < nrows) {
        const float* row = &lds[tid * LPAD];   // stride 41 -> 2-way bank alias (free)
        float obj = row[4];
        float score = 0.0f;
        if (obj > CONF_T) {
            float best = row[5] * obj;
#pragma unroll
            for (int j = 6; j < 40; ++j) best = fmaxf(best, row[j] * obj);
            if (best > CONF_T) score = best;
        }
        scores[(size_t)b * NN + rowBase + tid] = score;
        if (score > 0.0f) {
            unsigned int bits = __float_as_uint(score);
            unsigned int bk = (bits - BUCK_BASE) >> 12;
            if (bk > NBUCK - 1u) bk = NBUCK - 1u;
            atomicAdd(&hist[bk], 1u);
        }
    }
    __syncthreads();
    unsigned int* gh = ghist + b * NBUCK;
    for (int k = tid; k < NBUCK; k += 256) {
        unsigned int v = hist[k];
        if (v) atomicAdd(&gh[k], v);           // no return -> fire-and-forget
    }
}

// ============================================================
// Kernel 2: per-batch suffix-scan of global histogram -> cut bucket.
// cut = largest bucket c with suffix(c) >= PRE (0 if none).
// ============================================================
__global__ __launch_bounds__(1024) void k_cut(const unsigned int* __restrict__ ghist,
                                              unsigned int* __restrict__ cutv) {
    __shared__ int sA[1024], sB[1024];
    __shared__ int cutB;
    int b = blockIdx.x, tid = threadIdx.x;
    if (tid == 0) cutB = 0;
    __syncthreads();
    const unsigned int* gh = ghist + b * NBUCK;
    int h0 = gh[4 * tid + 0], h1 = gh[4 * tid + 1];
    int h2 = gh[4 * tid + 2], h3 = gh[4 * tid + 3];
    sA[tid] = h0 + h1 + h2 + h3;
    __syncthreads();
    int* src = sA;
    int* dst = sB;
    for (int off = 1; off < 1024; off <<= 1) {
        int x = src[tid];
        if (tid + off < 1024) x += src[tid + off];
        dst[tid] = x;
        __syncthreads();
        int* t_ = src; src = dst; dst = t_;
    }
    int nxt = (tid + 1 < 1024) ? src[tid + 1] : 0;
    int s3 = h3 + nxt;
    int s2 = h2 + s3;
    int s1 = h1 + s2;
    int s0 = h0 + s1;
    if (s0 >= PRE && s1 < PRE) cutB = 4 * tid + 0;
    if (s1 >= PRE && s2 < PRE) cutB = 4 * tid + 1;
    if (s2 >= PRE && s3 < PRE) cutB = 4 * tid + 2;
    if (s3 >= PRE && nxt < PRE) cutB = 4 * tid + 3;
    __syncthreads();
    if (tid == 0) cutv[b] = (unsigned int)cutB;
}

// ============================================================
// Kernel 3: full-grid gather of candidates >= cut bucket.
// key = (score_bits << 32) | ~idx  -> u64 desc == (value desc, idx asc)
// ============================================================
__global__ __launch_bounds__(256) void k_gather(const float* __restrict__ scores,
                                                const unsigned int* __restrict__ cutv,
                                                unsigned int* __restrict__ cnt,
                                                unsigned long long* __restrict__ cands) {
    int b = blockIdx.y;
    int i = blockIdx.x * 256 + threadIdx.x;
    if (i >= NN) return;
    float s = scores[(size_t)b * NN + i];
    if (s > 0.0f) {
        unsigned int bits = __float_as_uint(s);
        unsigned int bk = (bits - BUCK_BASE) >> 12;
        if (bk > NBUCK - 1u) bk = NBUCK - 1u;
        if (bk >= cutv[b]) {
            unsigned int pos = atomicAdd(&cnt[b], 1u);
            if (pos < CAP)
                cands[(size_t)b * CAP + pos] =
                    ((unsigned long long)bits << 32) | (unsigned int)(~(unsigned int)i);
        }
    }
}

// ============================================================
// Kernel 4: per-batch bitonic sort of candidate keys (desc), top-1024 gather:
// boxes (xyxy), score, cls_id (first-occurrence argmax of cls_j*obj)
// ============================================================
__global__ __launch_bounds__(1024) void k_sort(const unsigned int* __restrict__ cnt,
                                               const unsigned long long* __restrict__ cands,
                                               const float* __restrict__ pred,
                                               float4* __restrict__ boxesWS,
                                               float* __restrict__ svalWS,
                                               float* __restrict__ clsWS) {
    __shared__ unsigned long long keys[CAP];
    int b = blockIdx.x, tid = threadIdx.x;
    int M = (int)cnt[b];
    if (M > CAP) M = CAP;
    for (int k = tid; k < CAP; k += 1024)
        keys[k] = (k < M) ? cands[(size_t)b * CAP + k] : 0ull;
    __syncthreads();
    for (int k = 2; k <= CAP; k <<= 1) {
        for (int j = k >> 1; j > 0; j >>= 1) {
            int p = ((tid & ~(j - 1)) << 1) | (tid & (j - 1));
            int q = p | j;
            unsigned long long a = keys[p], c = keys[q];
            bool desc = (p & k) == 0;
            bool sw = desc ? (a < c) : (a > c);
            if (sw) { keys[p] = c; keys[q] = a; }
            __syncthreads();
        }
    }
    unsigned long long key = keys[tid];
    unsigned int bits = (unsigned int)(key >> 32);
    unsigned int idx = ~(unsigned int)key;
    float sc = __uint_as_float(bits);
    if (bits == 0u || idx >= NN) { idx = 0; sc = 0.0f; }   // pathological pad guard
    const float4* row = (const float4*)(pred + ((size_t)b * NN + idx) * RSTRIDE);
    float4 r0 = row[0];
    float4 r1 = row[1];
    float obj = r1.x;
    float best = r1.y * obj; int bj = 0;
    float p1 = r1.z * obj; if (p1 > best) { best = p1; bj = 1; }
    float p2 = r1.w * obj; if (p2 > best) { best = p2; bj = 2; }
#pragma unroll
    for (int kk = 2; kk <= 9; ++kk) {
        float4 r = row[kk];
        int base = (kk - 2) * 4 + 3;
        float q0 = r.x * obj; if (q0 > best) { best = q0; bj = base + 0; }
        float q1 = r.y * obj; if (q1 > best) { best = q1; bj = base + 1; }
        float q2 = r.z * obj; if (q2 > best) { best = q2; bj = base + 2; }
        float q3 = r.w * obj; if (q3 > best) { best = q3; bj = base + 3; }
    }
    float hx = r0.z * 0.5f;   // exact (power-of-two scale)
    float hy = r0.w * 0.5f;
    boxesWS[b * PRE + tid] = make_float4(r0.x - hx, r0.y - hy, r0.x + hx, r0.y + hy);
    svalWS[b * PRE + tid] = sc;
    clsWS[b * PRE + tid] = (float)bj;
}

// ============================================================
// Kernel 5: column-major suppression mask.
// maskC[b][j][c] bit l  <=>  i=64c+l < j  &&  valid[i]  &&  IoU(i,j) > 0.45
// ============================================================
__global__ __launch_bounds__(256) void k_mask(const float4* __restrict__ boxesWS,
                                              const float* __restrict__ svalWS,
                                              unsigned long long* __restrict__ maskC) {
    __shared__ float bx1[PRE], by1[PRE], bx2[PRE], by2[PRE], bar[PRE], bsv[PRE];
    int b = blockIdx.y, tid = threadIdx.x;
    for (int i = tid; i < PRE; i += 256) {
        float4 bx = boxesWS[b * PRE + i];
        bx1[i] = bx.x; by1[i] = bx.y; bx2[i] = bx.z; by2[i] = bx.w;
        float aw = fmaxf(bx.z - bx.x, 0.0f);
        float ah = fmaxf(bx.w - bx.y, 0.0f);
        bar[i] = aw * ah;
        bsv[i] = svalWS[b * PRE + i];
    }
    __syncthreads();
    int j = blockIdx.x * 4 + (tid >> 6);
    int lane = tid & 63;
    float jx1 = bx1[j], jy1 = by1[j], jx2 = bx2[j], jy2 = by2[j], ja = bar[j];
    unsigned long long* out = maskC + ((size_t)b * PRE + j) * 16;
    for (int c = 0; c < 16; ++c) {
        unsigned long long word = 0ull;
        if (c * 64 < j) {                      // wave-uniform branch
            int i = c * 64 + lane;
            bool bit = false;
            if (i < j && bsv[i] > 0.0f) {
                float ltx = fmaxf(bx1[i], jx1), lty = fmaxf(by1[i], jy1);
                float rbx = fminf(bx2[i], jx2), rby = fminf(by2[i], jy2);
                float wx = fmaxf(rbx - ltx, 0.0f);
                float wy = fmaxf(rby - lty, 0.0f);
                float inter = wx * wy;                       // two uses -> no contraction
                float denom = ((bar[i] + ja) - inter) + 1e-7f;
                bit = (inter / denom) > IOU_T;               // IEEE divide, like reference
            }
            word = __ballot(bit);
        }
        if (lane == 0) out[c] = word;
    }
}

// ============================================================
// Kernel 6: fixpoint NMS + exact top-300 ordering of where(keep, s, 0).
// ============================================================
__global__ __launch_bounds__(1024) void k_nms_out(const float4* __restrict__ boxesWS,
                                                  const float* __restrict__ svalWS,
                                                  const float* __restrict__ clsWS,
                                                  const unsigned long long* __restrict__ maskC,
                                                  float* __restrict__ out) {
    __shared__ unsigned long long supp[16], nsupp[16];
    __shared__ int changed;
    __shared__ int wtot[16], woff[17];
    int b = blockIdx.x, tid = threadIdx.x;
    int lane = tid & 63, w = tid >> 6;
    unsigned long long cm[16];
    const unsigned long long* mrow = maskC + ((size_t)b * PRE + tid) * 16;
#pragma unroll
    for (int k = 0; k < 16; ++k) cm[k] = mrow[k];
    float sv = svalWS[b * PRE + tid];
    if (tid < 16) supp[tid] = 0ull;
    __syncthreads();
    for (int it = 0; it < PRE + 2; ++it) {
        bool nb = false;
#pragma unroll
        for (int k = 0; k < 16; ++k) nb |= ((cm[k] & ~supp[k]) != 0ull);
        unsigned long long word = __ballot(nb);
        __syncthreads();
        if (lane == 0) nsupp[w] = word;
        if (tid == 0) changed = 0;
        __syncthreads();
        if (tid < 16) {
            if (nsupp[tid] != supp[tid]) changed = 1;
            supp[tid] = nsupp[tid];
        }
        __syncthreads();
        if (!changed) break;
    }
    bool keep = (sv > 0.0f) && !((supp[w] >> lane) & 1ull);
    unsigned long long km = __ballot(keep);
    int lp = __popcll(km & ((lane == 0) ? 0ull : ((1ull << lane) - 1ull)));
    if (lane == 0) wtot[w] = __popcll(km);
    __syncthreads();
    if (tid == 0) {
        int acc = 0;
        for (int k = 0; k < 16; ++k) { woff[k] = acc; acc += wtot[k]; }
        woff[16] = acc;
    }
    __syncthreads();
    int K = woff[16];
    int keptExcl = woff[w] + lp;
    int slot = keep ? keptExcl : (K + (tid - keptExcl));
    if (slot < MAXDET) {
        float4 bx = boxesWS[b * PRE + tid];
        float cv = clsWS[b * PRE + tid];
        float* o = out + ((size_t)b * MAXDET + slot) * 6;
        o[0] = bx.x; o[1] = bx.y; o[2] = bx.z; o[3] = bx.w;
        o[4] = keep ? sv : 0.0f;
        o[5] = cv;
    }
}

extern "C" void kernel_launch(void* const* d_in, const int* in_sizes, int n_in,
                              void* d_out, int out_size, void* d_ws, size_t ws_size,
                              hipStream_t stream) {
    const float* pred = (const float*)d_in[0];
    float* out = (float*)d_out;
    char* ws = (char*)d_ws;
    float* scores = (float*)(ws + SCORES_OFF);
    unsigned int* ghist = (unsigned int*)(ws + GHIST_OFF);
    unsigned int* cnt = (unsigned int*)(ws + CNT_OFF);
    unsigned int* cutv = (unsigned int*)(ws + CUT_OFF);
    unsigned long long* cands = (unsigned long long*)(ws + CANDS_OFF);
    float4* boxesWS = (float4*)(ws + BOXES_OFF);
    float* svalWS = (float*)(ws + SVAL_OFF);
    float* clsWS = (float*)(ws + CLS_OFF);
    unsigned long long* maskC = (unsigned long long*)(ws + MASK_OFF);

    hipMemsetAsync(ws + GHIST_OFF, 0, GHIST_BYTES + 64, stream);  // ghist + cnt
    k_score<<<dim3((NN + SROWS - 1) / SROWS, BB), 256, 0, stream>>>(pred, scores, ghist);
    k_cut<<<BB, 1024, 0, stream>>>(ghist, cutv);
    k_gather<<<dim3((NN + 255) / 256, BB), 256, 0, stream>>>(scores, cutv, cnt, cands);
    k_sort<<<BB, 1024, 0, stream>>>(cnt, cands, pred, boxesWS, svalWS, clsWS);
    k_mask<<<dim3(PRE / 4, BB), 256, 0, stream>>>(boxesWS, svalWS, maskC);
    k_nms_out<<<BB, 1024, 0, stream>>>(boxesWS, svalWS, clsWS, maskC, out);
}

// Round 3
// 555.108 us; speedup vs baseline: 1.0431x; 1.0431x over previous
//
#include <hip/hip_runtime.h>
#include <stdint.h>

#define BB 16
#define NN 102000
#define NCLS 35
#define RSTRIDE 40
#define PRE 1024
#define CAP 2048
#define MAXDET 300
#define NBUCK 4096
#define CONF_T 0.25f
#define IOU_T 0.45f
#define BUCK_BASE 0x3E800000u
#define SROWS 256
#define LPAD 37

// ---- workspace layout (bytes) ----
#define SCORES_OFF ((size_t)0)
#define SCORES_BYTES ((size_t)BB * NN * 4)                 // 6,528,000
#define GHIST_OFF (SCORES_OFF + SCORES_BYTES)
#define GHIST_BYTES ((size_t)BB * NBUCK * 4)               // 262,144
#define CNT_OFF (GHIST_OFF + GHIST_BYTES)                  // 64 B (16 u32 + pad)
#define CUT_OFF (CNT_OFF + 64)                             // 64 B
#define CANDS_OFF (CUT_OFF + 64)
#define CANDS_BYTES ((size_t)BB * CAP * 8)
#define BOXES_OFF (CANDS_OFF + CANDS_BYTES)
#define BOXES_BYTES ((size_t)BB * PRE * 16)
#define SVAL_OFF (BOXES_OFF + BOXES_BYTES)
#define SVAL_BYTES ((size_t)BB * PRE * 4)
#define CLS_OFF (SVAL_OFF + SVAL_BYTES)
#define CLS_BYTES ((size_t)BB * PRE * 4)
#define MASK_OFF (CLS_OFF + CLS_BYTES)
#define MASK_BYTES ((size_t)BB * PRE * 16 * 8)             // 2 MB

// ============================================================
// Kernel 1: score every box + per-batch global histogram of score bits.
// score = (obj>0.25 && conf>0.25) ? conf : 0, conf = max_j(cls_j*obj)
// Stages ONLY floats 4..39 (obj+cls) through LDS (37-pad, 2-way alias = free).
// Histogram ALIASES the staging LDS after compute -> 38 KB total, 4 blocks/CU.
// ============================================================
__global__ __launch_bounds__(256) void k_score(const float* __restrict__ pred,
                                               float* __restrict__ scores,
                                               unsigned int* __restrict__ ghist) {
    __shared__ float lds[SROWS * LPAD];        // 37,888 B (>= 16 KB hist)
    unsigned int* hist = (unsigned int*)lds;   // reused after compute phase
    int b = blockIdx.y, tid = threadIdx.x;
    int rowBase = blockIdx.x * SROWS;
    int nrows = NN - rowBase; if (nrows > SROWS) nrows = SROWS;
    // coalesced stage of float4 indices 1..9 of each row (floats 4..39)
    const float4* gp = (const float4*)(pred + ((size_t)b * NN + rowBase) * RSTRIDE);
    int nf4 = nrows * 9;
    for (int it = tid; it < nf4; it += 256) {
        int r = it / 9;
        int c = it - r * 9;
        float4 v = gp[r * 10 + 1 + c];
        float* d = &lds[r * LPAD + c * 4];
        d[0] = v.x; d[1] = v.y; d[2] = v.z; d[3] = v.w;
    }
    __syncthreads();
    float score = 0.0f;
    if (tid < nrows) {
        const float* row = &lds[tid * LPAD];   // stride 37 -> 2-way bank alias (free)
        float obj = row[0];
        if (obj > CONF_T) {
            float best = row[1] * obj;
#pragma unroll
            for (int j = 2; j <= 35; ++j) best = fmaxf(best, row[j] * obj);
            if (best > CONF_T) score = best;
        }
        scores[(size_t)b * NN + rowBase + tid] = score;
    }
    __syncthreads();                            // staging data dead; reuse as hist
    for (int k = tid; k < NBUCK; k += 256) hist[k] = 0u;
    __syncthreads();
    if (score > 0.0f) {
        unsigned int bits = __float_as_uint(score);
        unsigned int bk = (bits - BUCK_BASE) >> 12;
        if (bk > NBUCK - 1u) bk = NBUCK - 1u;
        atomicAdd(&hist[bk], 1u);
    }
    __syncthreads();
    unsigned int* gh = ghist + b * NBUCK;
    for (int k = tid; k < NBUCK; k += 256) {
        unsigned int v = hist[k];
        if (v) atomicAdd(&gh[k], v);           // no return -> fire-and-forget
    }
}

// ============================================================
// Kernel 2: per-batch suffix-scan of global histogram -> cut bucket.
// cut = largest bucket c with suffix(c) >= PRE (0 if none).
// ============================================================
__global__ __launch_bounds__(1024) void k_cut(const unsigned int* __restrict__ ghist,
                                              unsigned int* __restrict__ cutv) {
    __shared__ int sA[1024], sB[1024];
    __shared__ int cutB;
    int b = blockIdx.x, tid = threadIdx.x;
    if (tid == 0) cutB = 0;
    __syncthreads();
    const unsigned int* gh = ghist + b * NBUCK;
    int h0 = gh[4 * tid + 0], h1 = gh[4 * tid + 1];
    int h2 = gh[4 * tid + 2], h3 = gh[4 * tid + 3];
    sA[tid] = h0 + h1 + h2 + h3;
    __syncthreads();
    int* src = sA;
    int* dst = sB;
    for (int off = 1; off < 1024; off <<= 1) {
        int x = src[tid];
        if (tid + off < 1024) x += src[tid + off];
        dst[tid] = x;
        __syncthreads();
        int* t_ = src; src = dst; dst = t_;
    }
    int nxt = (tid + 1 < 1024) ? src[tid + 1] : 0;
    int s3 = h3 + nxt;
    int s2 = h2 + s3;
    int s1 = h1 + s2;
    int s0 = h0 + s1;
    if (s0 >= PRE && s1 < PRE) cutB = 4 * tid + 0;
    if (s1 >= PRE && s2 < PRE) cutB = 4 * tid + 1;
    if (s2 >= PRE && s3 < PRE) cutB = 4 * tid + 2;
    if (s3 >= PRE && nxt < PRE) cutB = 4 * tid + 3;
    __syncthreads();
    if (tid == 0) cutv[b] = (unsigned int)cutB;
}

// ============================================================
// Kernel 3: full-grid gather of candidates >= cut bucket.
// key = (score_bits << 32) | ~idx  -> u64 desc == (value desc, idx asc)
// ============================================================
__global__ __launch_bounds__(256) void k_gather(const float* __restrict__ scores,
                                                const unsigned int* __restrict__ cutv,
                                                unsigned int* __restrict__ cnt,
                                                unsigned long long* __restrict__ cands) {
    int b = blockIdx.y;
    int i = blockIdx.x * 256 + threadIdx.x;
    if (i >= NN) return;
    float s = scores[(size_t)b * NN + i];
    if (s > 0.0f) {
        unsigned int bits = __float_as_uint(s);
        unsigned int bk = (bits - BUCK_BASE) >> 12;
        if (bk > NBUCK - 1u) bk = NBUCK - 1u;
        if (bk >= cutv[b]) {
            unsigned int pos = atomicAdd(&cnt[b], 1u);
            if (pos < CAP)
                cands[(size_t)b * CAP + pos] =
                    ((unsigned long long)bits << 32) | (unsigned int)(~(unsigned int)i);
        }
    }
}

// ============================================================
// Kernel 4: per-batch bitonic sort of candidate keys (desc), top-1024 gather:
// boxes (xyxy), score, cls_id (first-occurrence argmax of cls_j*obj)
// ============================================================
__global__ __launch_bounds__(1024) void k_sort(const unsigned int* __restrict__ cnt,
                                               const unsigned long long* __restrict__ cands,
                                               const float* __restrict__ pred,
                                               float4* __restrict__ boxesWS,
                                               float* __restrict__ svalWS,
                                               float* __restrict__ clsWS) {
    __shared__ unsigned long long keys[CAP];
    int b = blockIdx.x, tid = threadIdx.x;
    int M = (int)cnt[b];
    if (M > CAP) M = CAP;
    for (int k = tid; k < CAP; k += 1024)
        keys[k] = (k < M) ? cands[(size_t)b * CAP + k] : 0ull;
    __syncthreads();
    for (int k = 2; k <= CAP; k <<= 1) {
        for (int j = k >> 1; j > 0; j >>= 1) {
            int p = ((tid & ~(j - 1)) << 1) | (tid & (j - 1));
            int q = p | j;
            unsigned long long a = keys[p], c = keys[q];
            bool desc = (p & k) == 0;
            bool sw = desc ? (a < c) : (a > c);
            if (sw) { keys[p] = c; keys[q] = a; }
            __syncthreads();
        }
    }
    unsigned long long key = keys[tid];
    unsigned int bits = (unsigned int)(key >> 32);
    unsigned int idx = ~(unsigned int)key;
    float sc = __uint_as_float(bits);
    if (bits == 0u || idx >= NN) { idx = 0; sc = 0.0f; }   // pathological pad guard
    const float4* row = (const float4*)(pred + ((size_t)b * NN + idx) * RSTRIDE);
    float4 r0 = row[0];
    float4 r1 = row[1];
    float obj = r1.x;
    float best = r1.y * obj; int bj = 0;
    float p1 = r1.z * obj; if (p1 > best) { best = p1; bj = 1; }
    float p2 = r1.w * obj; if (p2 > best) { best = p2; bj = 2; }
#pragma unroll
    for (int kk = 2; kk <= 9; ++kk) {
        float4 r = row[kk];
        int base = (kk - 2) * 4 + 3;
        float q0 = r.x * obj; if (q0 > best) { best = q0; bj = base + 0; }
        float q1 = r.y * obj; if (q1 > best) { best = q1; bj = base + 1; }
        float q2 = r.z * obj; if (q2 > best) { best = q2; bj = base + 2; }
        float q3 = r.w * obj; if (q3 > best) { best = q3; bj = base + 3; }
    }
    float hx = r0.z * 0.5f;   // exact (power-of-two scale)
    float hy = r0.w * 0.5f;
    boxesWS[b * PRE + tid] = make_float4(r0.x - hx, r0.y - hy, r0.x + hx, r0.y + hy);
    svalWS[b * PRE + tid] = sc;
    clsWS[b * PRE + tid] = (float)bj;
}

// ============================================================
// Kernel 5: column-major suppression mask.
// maskC[b][j][c] bit l  <=>  i=64c+l < j  &&  valid[i]  &&  IoU(i,j) > 0.45
// ============================================================
__global__ __launch_bounds__(256) void k_mask(const float4* __restrict__ boxesWS,
                                              const float* __restrict__ svalWS,
                                              unsigned long long* __restrict__ maskC) {
    __shared__ float bx1[PRE], by1[PRE], bx2[PRE], by2[PRE], bar[PRE], bsv[PRE];
    int b = blockIdx.y, tid = threadIdx.x;
    for (int i = tid; i < PRE; i += 256) {
        float4 bx = boxesWS[b * PRE + i];
        bx1[i] = bx.x; by1[i] = bx.y; bx2[i] = bx.z; by2[i] = bx.w;
        float aw = fmaxf(bx.z - bx.x, 0.0f);
        float ah = fmaxf(bx.w - bx.y, 0.0f);
        bar[i] = aw * ah;
        bsv[i] = svalWS[b * PRE + i];
    }
    __syncthreads();
    int j = blockIdx.x * 4 + (tid >> 6);
    int lane = tid & 63;
    float jx1 = bx1[j], jy1 = by1[j], jx2 = bx2[j], jy2 = by2[j], ja = bar[j];
    unsigned long long* out = maskC + ((size_t)b * PRE + j) * 16;
    for (int c = 0; c < 16; ++c) {
        unsigned long long word = 0ull;
        if (c * 64 < j) {                      // wave-uniform branch
            int i = c * 64 + lane;
            bool bit = false;
            if (i < j && bsv[i] > 0.0f) {
                float ltx = fmaxf(bx1[i], jx1), lty = fmaxf(by1[i], jy1);
                float rbx = fminf(bx2[i], jx2), rby = fminf(by2[i], jy2);
                float wx = fmaxf(rbx - ltx, 0.0f);
                float wy = fmaxf(rby - lty, 0.0f);
                float inter = wx * wy;                       // two uses -> no contraction
                float denom = ((bar[i] + ja) - inter) + 1e-7f;
                bit = (inter / denom) > IOU_T;               // IEEE divide, like reference
            }
            word = __ballot(bit);
        }
        if (lane == 0) out[c] = word;
    }
}

// ============================================================
// Kernel 6: fixpoint NMS + exact top-300 ordering of where(keep, s, 0).
// ============================================================
__global__ __launch_bounds__(1024) void k_nms_out(const float4* __restrict__ boxesWS,
                                                  const float* __restrict__ svalWS,
                                                  const float* __restrict__ clsWS,
                                                  const unsigned long long* __restrict__ maskC,
                                                  float* __restrict__ out) {
    __shared__ unsigned long long supp[16], nsupp[16];
    __shared__ int changed;
    __shared__ int wtot[16], woff[17];
    int b = blockIdx.x, tid = threadIdx.x;
    int lane = tid & 63, w = tid >> 6;
    unsigned long long cm[16];
    const unsigned long long* mrow = maskC + ((size_t)b * PRE + tid) * 16;
#pragma unroll
    for (int k = 0; k < 16; ++k) cm[k] = mrow[k];
    float sv = svalWS[b * PRE + tid];
    if (tid < 16) supp[tid] = 0ull;
    __syncthreads();
    for (int it = 0; it < PRE + 2; ++it) {
        bool nb = false;
#pragma unroll
        for (int k = 0; k < 16; ++k) nb |= ((cm[k] & ~supp[k]) != 0ull);
        unsigned long long word = __ballot(nb);
        __syncthreads();
        if (lane == 0) nsupp[w] = word;
        if (tid == 0) changed = 0;
        __syncthreads();
        if (tid < 16) {
            if (nsupp[tid] != supp[tid]) changed = 1;
            supp[tid] = nsupp[tid];
        }
        __syncthreads();
        if (!changed) break;
    }
    bool keep = (sv > 0.0f) && !((supp[w] >> lane) & 1ull);
    unsigned long long km = __ballot(keep);
    int lp = __popcll(km & ((lane == 0) ? 0ull : ((1ull << lane) - 1ull)));
    if (lane == 0) wtot[w] = __popcll(km);
    __syncthreads();
    if (tid == 0) {
        int acc = 0;
        for (int k = 0; k < 16; ++k) { woff[k] = acc; acc += wtot[k]; }
        woff[16] = acc;
    }
    __syncthreads();
    int K = woff[16];
    int keptExcl = woff[w] + lp;
    int slot = keep ? keptExcl : (K + (tid - keptExcl));
    if (slot < MAXDET) {
        float4 bx = boxesWS[b * PRE + tid];
        float cv = clsWS[b * PRE + tid];
        float* o = out + ((size_t)b * MAXDET + slot) * 6;
        o[0] = bx.x; o[1] = bx.y; o[2] = bx.z; o[3] = bx.w;
        o[4] = keep ? sv : 0.0f;
        o[5] = cv;
    }
}

extern "C" void kernel_launch(void* const* d_in, const int* in_sizes, int n_in,
                              void* d_out, int out_size, void* d_ws, size_t ws_size,
                              hipStream_t stream) {
    const float* pred = (const float*)d_in[0];
    float* out = (float*)d_out;
    char* ws = (char*)d_ws;
    float* scores = (float*)(ws + SCORES_OFF);
    unsigned int* ghist = (unsigned int*)(ws + GHIST_OFF);
    unsigned int* cnt = (unsigned int*)(ws + CNT_OFF);
    unsigned int* cutv = (unsigned int*)(ws + CUT_OFF);
    unsigned long long* cands = (unsigned long long*)(ws + CANDS_OFF);
    float4* boxesWS = (float4*)(ws + BOXES_OFF);
    float* svalWS = (float*)(ws + SVAL_OFF);
    float* clsWS = (float*)(ws + CLS_OFF);
    unsigned long long* maskC = (unsigned long long*)(ws + MASK_OFF);

    hipMemsetAsync(ws + GHIST_OFF, 0, GHIST_BYTES + 64, stream);  // ghist + cnt
    k_score<<<dim3((NN + SROWS - 1) / SROWS, BB), 256, 0, stream>>>(pred, scores, ghist);
    k_cut<<<BB, 1024, 0, stream>>>(ghist, cutv);
    k_gather<<<dim3((NN + 255) / 256, BB), 256, 0, stream>>>(scores, cutv, cnt, cands);
    k_sort<<<BB, 1024, 0, stream>>>(cnt, cands, pred, boxesWS, svalWS, clsWS);
    k_mask<<<dim3(PRE / 4, BB), 256, 0, stream>>>(boxesWS, svalWS, maskC);
    k_nms_out<<<BB, 1024, 0, stream>>>(boxesWS, svalWS, clsWS, maskC, out);
}

// Round 4
// 434.724 us; speedup vs baseline: 1.3320x; 1.2769x over previous
//
#include <hip/hip_runtime.h>
#include <stdint.h>

#define BB 16
#define NN 102000
#define NCLS 35
#define RSTRIDE 40
#define PRE 1024
#define CAP 2048
#define MAXDET 300
#define NBUCK 4096
#define CONF_T 0.25f
#define IOU_T 0.45f
#define BUCK_BASE 0x3E800000u
#define SROWS 256

// ---- workspace layout (bytes) ----
#define SCORES_OFF ((size_t)0)
#define SCORES_BYTES ((size_t)BB * NN * 4)                 // 6,528,000
#define GHIST_OFF (SCORES_OFF + SCORES_BYTES)
#define GHIST_BYTES ((size_t)BB * NBUCK * 4)               // 262,144
#define CUT_OFF (GHIST_OFF + GHIST_BYTES)                  // 64 B
#define BOXES_OFF (CUT_OFF + 64)
#define BOXES_BYTES ((size_t)BB * PRE * 16)
#define SVAL_OFF (BOXES_OFF + BOXES_BYTES)
#define SVAL_BYTES ((size_t)BB * PRE * 4)
#define CLS_OFF (SVAL_OFF + SVAL_BYTES)
#define CLS_BYTES ((size_t)BB * PRE * 4)
#define MASK_OFF (CLS_OFF + CLS_BYTES)
#define MASK_BYTES ((size_t)BB * PRE * 16 * 8)             // 2 MB

// ============================================================
// Kernel 1: score every box + per-batch global histogram of score bits.
// score = (obj>0.25 && conf>0.25) ? conf : 0, conf = max_j(cls_j*obj)
// Stage floats 4..39 (obj+cls) as 9 float4/row, row stride 36 words:
//  - b128 reads: bank-quad = (l+c) mod 8 -> perfectly balanced, no conflict
//  - 36,864 B LDS -> 4 blocks/CU, single barrier
// Histogram: direct fire-and-forget global atomics (256 rows into 4096
// buckets ~never collide, so LDS pre-aggregation saves nothing).
// ============================================================
__global__ __launch_bounds__(256) void k_score(const float* __restrict__ pred,
                                               float* __restrict__ scores,
                                               unsigned int* __restrict__ ghist) {
    __shared__ float4 lds4[SROWS * 9];         // 36,864 B
    int b = blockIdx.y, tid = threadIdx.x;
    int rowBase = blockIdx.x * SROWS;
    int nrows = NN - rowBase; if (nrows > SROWS) nrows = SROWS;
    const float4* gp = (const float4*)(pred + ((size_t)b * NN + rowBase) * RSTRIDE);
    int nf4 = nrows * 9;
    for (int it = tid; it < nf4; it += 256) {
        int r = it / 9;
        int c = it - r * 9;
        lds4[r * 9 + c] = gp[r * 10 + 1 + c];  // skip xywh float4
    }
    __syncthreads();
    if (tid < nrows) {
        const float4* row4 = &lds4[tid * 9];
        float4 v0 = row4[0];                   // [obj, cls0, cls1, cls2]
        float obj = v0.x;
        float score = 0.0f;
        if (obj > CONF_T) {
            float best = v0.y * obj;
            best = fmaxf(best, v0.z * obj);
            best = fmaxf(best, v0.w * obj);
#pragma unroll
            for (int c = 1; c < 9; ++c) {
                float4 v = row4[c];
                best = fmaxf(best, v.x * obj);
                best = fmaxf(best, v.y * obj);
                best = fmaxf(best, v.z * obj);
                best = fmaxf(best, v.w * obj);
            }
            if (best > CONF_T) score = best;
        }
        scores[(size_t)b * NN + rowBase + tid] = score;
        if (score > 0.0f) {
            unsigned int bits = __float_as_uint(score);
            unsigned int bk = (bits - BUCK_BASE) >> 12;
            if (bk > NBUCK - 1u) bk = NBUCK - 1u;
            atomicAdd(&ghist[b * NBUCK + bk], 1u);   // no return -> fire-and-forget
        }
    }
}

// ============================================================
// Kernel 2: per-batch suffix-scan of global histogram -> cut bucket.
// cut = largest bucket c with suffix(c) >= PRE (0 if none).
// ============================================================
__global__ __launch_bounds__(1024) void k_cut(const unsigned int* __restrict__ ghist,
                                              unsigned int* __restrict__ cutv) {
    __shared__ int sA[1024], sB[1024];
    __shared__ int cutB;
    int b = blockIdx.x, tid = threadIdx.x;
    if (tid == 0) cutB = 0;
    __syncthreads();
    const unsigned int* gh = ghist + b * NBUCK;
    int h0 = gh[4 * tid + 0], h1 = gh[4 * tid + 1];
    int h2 = gh[4 * tid + 2], h3 = gh[4 * tid + 3];
    sA[tid] = h0 + h1 + h2 + h3;
    __syncthreads();
    int* src = sA;
    int* dst = sB;
    for (int off = 1; off < 1024; off <<= 1) {
        int x = src[tid];
        if (tid + off < 1024) x += src[tid + off];
        dst[tid] = x;
        __syncthreads();
        int* t_ = src; src = dst; dst = t_;
    }
    int nxt = (tid + 1 < 1024) ? src[tid + 1] : 0;
    int s3 = h3 + nxt;
    int s2 = h2 + s3;
    int s1 = h1 + s2;
    int s0 = h0 + s1;
    if (s0 >= PRE && s1 < PRE) cutB = 4 * tid + 0;
    if (s1 >= PRE && s2 < PRE) cutB = 4 * tid + 1;
    if (s2 >= PRE && s3 < PRE) cutB = 4 * tid + 2;
    if (s3 >= PRE && nxt < PRE) cutB = 4 * tid + 3;
    __syncthreads();
    if (tid == 0) cutv[b] = (unsigned int)cutB;
}

// ============================================================
// Kernel 3: per-batch gather (>= cut bucket) straight into LDS, bitonic
// sort desc, top-1024 gather of boxes/score/cls_id.
// key = (score_bits << 32) | ~idx  -> u64 desc == (value desc, idx asc)
// ============================================================
__global__ __launch_bounds__(1024) void k_sort(const float* __restrict__ scores,
                                               const unsigned int* __restrict__ cutv,
                                               const float* __restrict__ pred,
                                               float4* __restrict__ boxesWS,
                                               float* __restrict__ svalWS,
                                               float* __restrict__ clsWS) {
    __shared__ unsigned long long keys[CAP];
    __shared__ unsigned int nloc;
    int b = blockIdx.x, tid = threadIdx.x;
    unsigned int cut = cutv[b];
    if (tid == 0) nloc = 0u;
    for (int k = tid; k < CAP; k += 1024) keys[k] = 0ull;
    __syncthreads();
    // scan this batch's score segment (float4: NN*4 bytes = 25500 * 16)
    const float4* sb4 = (const float4*)(scores + (size_t)b * NN);
    for (int it = tid; it < NN / 4; it += 1024) {
        float4 s4 = sb4[it];
        float sv[4] = {s4.x, s4.y, s4.z, s4.w};
#pragma unroll
        for (int u = 0; u < 4; ++u) {
            float s = sv[u];
            if (s > 0.0f) {
                unsigned int bits = __float_as_uint(s);
                unsigned int bk = (bits - BUCK_BASE) >> 12;
                if (bk > NBUCK - 1u) bk = NBUCK - 1u;
                if (bk >= cut) {
                    unsigned int pos = atomicAdd(&nloc, 1u);
                    unsigned int idx = (unsigned int)(it * 4 + u);
                    if (pos < CAP)
                        keys[pos] = ((unsigned long long)bits << 32) |
                                    (unsigned int)(~idx);
                }
            }
        }
    }
    __syncthreads();
    for (int k = 2; k <= CAP; k <<= 1) {
        for (int j = k >> 1; j > 0; j >>= 1) {
            int p = ((tid & ~(j - 1)) << 1) | (tid & (j - 1));
            int q = p | j;
            unsigned long long a = keys[p], c = keys[q];
            bool desc = (p & k) == 0;
            bool sw = desc ? (a < c) : (a > c);
            if (sw) { keys[p] = c; keys[q] = a; }
            __syncthreads();
        }
    }
    unsigned long long key = keys[tid];
    unsigned int bits = (unsigned int)(key >> 32);
    unsigned int idx = ~(unsigned int)key;
    float sc = __uint_as_float(bits);
    if (bits == 0u || idx >= NN) { idx = 0; sc = 0.0f; }   // pad guard
    const float4* row = (const float4*)(pred + ((size_t)b * NN + idx) * RSTRIDE);
    float4 r0 = row[0];
    float4 r1 = row[1];
    float obj = r1.x;
    float best = r1.y * obj; int bj = 0;
    float p1 = r1.z * obj; if (p1 > best) { best = p1; bj = 1; }
    float p2 = r1.w * obj; if (p2 > best) { best = p2; bj = 2; }
#pragma unroll
    for (int kk = 2; kk <= 9; ++kk) {
        float4 r = row[kk];
        int base = (kk - 2) * 4 + 3;
        float q0 = r.x * obj; if (q0 > best) { best = q0; bj = base + 0; }
        float q1 = r.y * obj; if (q1 > best) { best = q1; bj = base + 1; }
        float q2 = r.z * obj; if (q2 > best) { best = q2; bj = base + 2; }
        float q3 = r.w * obj; if (q3 > best) { best = q3; bj = base + 3; }
    }
    float hx = r0.z * 0.5f;   // exact (power-of-two scale)
    float hy = r0.w * 0.5f;
    boxesWS[b * PRE + tid] = make_float4(r0.x - hx, r0.y - hy, r0.x + hx, r0.y + hy);
    svalWS[b * PRE + tid] = sc;
    clsWS[b * PRE + tid] = (float)bj;
}

// ============================================================
// Kernel 4: column-major suppression mask.
// maskC[b][j][c] bit l  <=>  i=64c+l < j  &&  valid[i]  &&  IoU(i,j) > 0.45
// ============================================================
__global__ __launch_bounds__(256) void k_mask(const float4* __restrict__ boxesWS,
                                              const float* __restrict__ svalWS,
                                              unsigned long long* __restrict__ maskC) {
    __shared__ float bx1[PRE], by1[PRE], bx2[PRE], by2[PRE], bar[PRE], bsv[PRE];
    int b = blockIdx.y, tid = threadIdx.x;
    for (int i = tid; i < PRE; i += 256) {
        float4 bx = boxesWS[b * PRE + i];
        bx1[i] = bx.x; by1[i] = bx.y; bx2[i] = bx.z; by2[i] = bx.w;
        float aw = fmaxf(bx.z - bx.x, 0.0f);
        float ah = fmaxf(bx.w - bx.y, 0.0f);
        bar[i] = aw * ah;
        bsv[i] = svalWS[b * PRE + i];
    }
    __syncthreads();
    int j = blockIdx.x * 4 + (tid >> 6);
    int lane = tid & 63;
    float jx1 = bx1[j], jy1 = by1[j], jx2 = bx2[j], jy2 = by2[j], ja = bar[j];
    unsigned long long* out = maskC + ((size_t)b * PRE + j) * 16;
    for (int c = 0; c < 16; ++c) {
        unsigned long long word = 0ull;
        if (c * 64 < j) {                      // wave-uniform branch
            int i = c * 64 + lane;
            bool bit = false;
            if (i < j && bsv[i] > 0.0f) {
                float ltx = fmaxf(bx1[i], jx1), lty = fmaxf(by1[i], jy1);
                float rbx = fminf(bx2[i], jx2), rby = fminf(by2[i], jy2);
                float wx = fmaxf(rbx - ltx, 0.0f);
                float wy = fmaxf(rby - lty, 0.0f);
                float inter = wx * wy;                       // two uses -> no contraction
                float denom = ((bar[i] + ja) - inter) + 1e-7f;
                bit = (inter / denom) > IOU_T;               // IEEE divide, like reference
            }
            word = __ballot(bit);
        }
        if (lane == 0) out[c] = word;
    }
}

// ============================================================
// Kernel 5: fixpoint NMS + exact top-300 ordering of where(keep, s, 0).
// ============================================================
__global__ __launch_bounds__(1024) void k_nms_out(const float4* __restrict__ boxesWS,
                                                  const float* __restrict__ svalWS,
                                                  const float* __restrict__ clsWS,
                                                  const unsigned long long* __restrict__ maskC,
                                                  float* __restrict__ out) {
    __shared__ unsigned long long supp[16], nsupp[16];
    __shared__ int changed;
    __shared__ int wtot[16], woff[17];
    int b = blockIdx.x, tid = threadIdx.x;
    int lane = tid & 63, w = tid >> 6;
    unsigned long long cm[16];
    const unsigned long long* mrow = maskC + ((size_t)b * PRE + tid) * 16;
#pragma unroll
    for (int k = 0; k < 16; ++k) cm[k] = mrow[k];
    float sv = svalWS[b * PRE + tid];
    if (tid < 16) supp[tid] = 0ull;
    __syncthreads();
    for (int it = 0; it < PRE + 2; ++it) {
        bool nb = false;
#pragma unroll
        for (int k = 0; k < 16; ++k) nb |= ((cm[k] & ~supp[k]) != 0ull);
        unsigned long long word = __ballot(nb);
        __syncthreads();
        if (lane == 0) nsupp[w] = word;
        if (tid == 0) changed = 0;
        __syncthreads();
        if (tid < 16) {
            if (nsupp[tid] != supp[tid]) changed = 1;
            supp[tid] = nsupp[tid];
        }
        __syncthreads();
        if (!changed) break;
    }
    bool keep = (sv > 0.0f) && !((supp[w] >> lane) & 1ull);
    unsigned long long km = __ballot(keep);
    int lp = __popcll(km & ((lane == 0) ? 0ull : ((1ull << lane) - 1ull)));
    if (lane == 0) wtot[w] = __popcll(km);
    __syncthreads();
    if (tid == 0) {
        int acc = 0;
        for (int k = 0; k < 16; ++k) { woff[k] = acc; acc += wtot[k]; }
        woff[16] = acc;
    }
    __syncthreads();
    int K = woff[16];
    int keptExcl = woff[w] + lp;
    int slot = keep ? keptExcl : (K + (tid - keptExcl));
    if (slot < MAXDET) {
        float4 bx = boxesWS[b * PRE + tid];
        float cv = clsWS[b * PRE + tid];
        float* o = out + ((size_t)b * MAXDET + slot) * 6;
        o[0] = bx.x; o[1] = bx.y; o[2] = bx.z; o[3] = bx.w;
        o[4] = keep ? sv : 0.0f;
        o[5] = cv;
    }
}

extern "C" void kernel_launch(void* const* d_in, const int* in_sizes, int n_in,
                              void* d_out, int out_size, void* d_ws, size_t ws_size,
                              hipStream_t stream) {
    const float* pred = (const float*)d_in[0];
    float* out = (float*)d_out;
    char* ws = (char*)d_ws;
    float* scores = (float*)(ws + SCORES_OFF);
    unsigned int* ghist = (unsigned int*)(ws + GHIST_OFF);
    unsigned int* cutv = (unsigned int*)(ws + CUT_OFF);
    float4* boxesWS = (float4*)(ws + BOXES_OFF);
    float* svalWS = (float*)(ws + SVAL_OFF);
    float* clsWS = (float*)(ws + CLS_OFF);
    unsigned long long* maskC = (unsigned long long*)(ws + MASK_OFF);

    hipMemsetAsync(ws + GHIST_OFF, 0, GHIST_BYTES, stream);
    k_score<<<dim3((NN + SROWS - 1) / SROWS, BB), 256, 0, stream>>>(pred, scores, ghist);
    k_cut<<<BB, 1024, 0, stream>>>(ghist, cutv);
    k_sort<<<BB, 1024, 0, stream>>>(scores, cutv, pred, boxesWS, svalWS, clsWS);
    k_mask<<<dim3(PRE / 4, BB), 256, 0, stream>>>(boxesWS, svalWS, maskC);
    k_nms_out<<<BB, 1024, 0, stream>>>(boxesWS, svalWS, clsWS, maskC, out);
}